// Round 1
// baseline (699.802 us; speedup 1.0000x reference)
//
#include <hip/hip_runtime.h>

#define N_TOK 32768
#define HID   1024
#define NE    8
#define NI    2048
#define CAP   4096

typedef short  s16x8 __attribute__((ext_vector_type(8)));
typedef float  f32x4 __attribute__((ext_vector_type(4)));

__device__ inline unsigned short f2bf(float f) {
    unsigned int u = __builtin_bit_cast(unsigned int, f);
    u += 0x7fffu + ((u >> 16) & 1u);
    return (unsigned short)(u >> 16);
}

// ---------------- Router: fp32 dot, top-2, softmax ----------------
__global__ __launch_bounds__(256) void router_kernel(
    const float* __restrict__ x, const float* __restrict__ emb,
    int2* __restrict__ r_e, float2* __restrict__ r_w)
{
    int token = blockIdx.x * 4 + (threadIdx.x >> 6);
    int lane  = threadIdx.x & 63;
    const float* xr = x + (size_t)token * HID;

    float a[NE];
#pragma unroll
    for (int e = 0; e < NE; ++e) a[e] = 0.f;

    for (int j = 0; j < HID / 64; ++j) {
        int idx = lane + j * 64;
        float xv = xr[idx];
#pragma unroll
        for (int e = 0; e < NE; ++e) a[e] += xv * emb[e * HID + idx];
    }
#pragma unroll
    for (int e = 0; e < NE; ++e) {
        for (int off = 32; off; off >>= 1) a[e] += __shfl_xor(a[e], off);
    }
    if (lane == 0) {
        float v1 = -1e30f, v2 = -1e30f; int i1 = 0, i2 = 0;
#pragma unroll
        for (int e = 0; e < NE; ++e) {
            float v = a[e];
            if (v > v1) { v2 = v1; i2 = i1; v1 = v; i1 = e; }
            else if (v > v2) { v2 = v; i2 = e; }
        }
        float ex = __expf(v2 - v1);
        float w1 = 1.f / (1.f + ex);
        float w2 = ex / (1.f + ex);
        r_e[token] = make_int2(i1, i2);
        r_w[token] = make_float2(w1, w2);
    }
}

// ---------------- Capacity: count / prefix / ordered assign ----------------
__global__ __launch_bounds__(1024) void count_kernel(
    const int2* __restrict__ r_e, int* __restrict__ bc)
{
    __shared__ int cnt[NE];
    if (threadIdx.x < NE) cnt[threadIdx.x] = 0;
    __syncthreads();
    int n = blockIdx.x * 1024 + threadIdx.x;
    int2 e = r_e[n];
    atomicAdd(&cnt[e.x], 1);
    atomicAdd(&cnt[e.y], 1);
    __syncthreads();
    if (threadIdx.x < NE) bc[blockIdx.x * NE + threadIdx.x] = cnt[threadIdx.x];
}

__global__ void prefix_kernel(const int* __restrict__ bc, int* __restrict__ bb)
{
    int e = threadIdx.x;
    if (e >= NE) return;
    int run = 0;
    for (int b = 0; b < N_TOK / 1024; ++b) {
        bb[b * NE + e] = run;
        run += bc[b * NE + e];
    }
}

__global__ __launch_bounds__(1024) void assign_kernel(
    const int2* __restrict__ r_e, const float2* __restrict__ r_w,
    const int* __restrict__ bb,
    int* __restrict__ tok_list, float* __restrict__ w_list)
{
    __shared__ int wavecnt[16][NE];
    __shared__ int waveoff[16][NE];
    int tid = threadIdx.x, lane = tid & 63, wv = tid >> 6;
    int n = blockIdx.x * 1024 + tid;
    int2 e = r_e[n];
    float2 w = r_w[n];
    unsigned long long below = (1ull << lane) - 1ull;
    int rank0 = 0, rank1 = 0;
#pragma unroll
    for (int ex = 0; ex < NE; ++ex) {
        unsigned long long m = __ballot(e.x == ex || e.y == ex);
        if (lane == 0) wavecnt[wv][ex] = __popcll(m);
        int r = __popcll(m & below);
        if (e.x == ex) rank0 = r;
        if (e.y == ex) rank1 = r;
    }
    __syncthreads();
    if (tid < NE) {
        int run = 0;
        for (int w2 = 0; w2 < 16; ++w2) { waveoff[w2][tid] = run; run += wavecnt[w2][tid]; }
    }
    __syncthreads();
    int s0 = bb[blockIdx.x * NE + e.x] + waveoff[wv][e.x] + rank0;
    int s1 = bb[blockIdx.x * NE + e.y] + waveoff[wv][e.y] + rank1;
    if (s0 < CAP) { tok_list[e.x * CAP + s0] = n; w_list[e.x * CAP + s0] = w.x; }
    if (s1 < CAP) { tok_list[e.y * CAP + s1] = n; w_list[e.y * CAP + s1] = w.y; }
}

// ---------------- GEMM1: inter[c,i] = relu(sum_h x[tok[c],h] * W1[e][i,h]) ----------------
__global__ __launch_bounds__(256) void gemm1_kernel(
    const float* __restrict__ x, const float* __restrict__ W1,
    const int* __restrict__ tok_list,
    unsigned short* __restrict__ inter,   // bf16 [z][CAP][NI]
    int expert_base, long inter_stride)
{
    const int e    = expert_base + blockIdx.z;
    const int tm   = blockIdx.y;   // 0..31
    const int tn   = blockIdx.x;   // 0..15
    const int tid  = threadIdx.x;
    const int lane = tid & 63;
    const int wave = tid >> 6;
    const int wm   = (wave >> 1) * 64;
    const int wn   = (wave & 1) * 64;

    __shared__ __align__(16) unsigned short Alds[128][40];
    __shared__ __align__(16) unsigned short Blds[128][40];

    const int srow = tid >> 2;        // 0..63
    const int sk0  = (tid & 3) * 8;   // 0,8,16,24

    const int* tl = tok_list + e * CAP + tm * 128;
    int tokA[2];
    tokA[0] = tl[srow];
    tokA[1] = tl[srow + 64];
    const float* w1e = W1 + (size_t)e * NI * HID;

    f32x4 acc[4][4];
#pragma unroll
    for (int i = 0; i < 4; ++i)
#pragma unroll
        for (int j = 0; j < 4; ++j) acc[i][j] = (f32x4)0.f;

    for (int k0 = 0; k0 < HID; k0 += 32) {
#pragma unroll
        for (int r2 = 0; r2 < 2; ++r2) {
            int row = srow + r2 * 64;
            const float* srcA = x + (size_t)tokA[r2] * HID + k0 + sk0;
            float4 a0 = *reinterpret_cast<const float4*>(srcA);
            float4 a1 = *reinterpret_cast<const float4*>(srcA + 4);
            uint4 pa;
            pa.x = f2bf(a0.x) | ((unsigned)f2bf(a0.y) << 16);
            pa.y = f2bf(a0.z) | ((unsigned)f2bf(a0.w) << 16);
            pa.z = f2bf(a1.x) | ((unsigned)f2bf(a1.y) << 16);
            pa.w = f2bf(a1.z) | ((unsigned)f2bf(a1.w) << 16);
            *reinterpret_cast<uint4*>(&Alds[row][sk0]) = pa;

            const float* srcB = w1e + (size_t)(tn * 128 + row) * HID + k0 + sk0;
            float4 b0 = *reinterpret_cast<const float4*>(srcB);
            float4 b1 = *reinterpret_cast<const float4*>(srcB + 4);
            uint4 pb;
            pb.x = f2bf(b0.x) | ((unsigned)f2bf(b0.y) << 16);
            pb.y = f2bf(b0.z) | ((unsigned)f2bf(b0.w) << 16);
            pb.z = f2bf(b1.x) | ((unsigned)f2bf(b1.y) << 16);
            pb.w = f2bf(b1.z) | ((unsigned)f2bf(b1.w) << 16);
            *reinterpret_cast<uint4*>(&Blds[row][sk0]) = pb;
        }
        __syncthreads();
        s16x8 af[4], bfr[4];
#pragma unroll
        for (int mi = 0; mi < 4; ++mi)
            af[mi] = *reinterpret_cast<const s16x8*>(&Alds[wm + mi * 16 + (lane & 15)][(lane >> 4) * 8]);
#pragma unroll
        for (int ni = 0; ni < 4; ++ni)
            bfr[ni] = *reinterpret_cast<const s16x8*>(&Blds[wn + ni * 16 + (lane & 15)][(lane >> 4) * 8]);
#pragma unroll
        for (int mi = 0; mi < 4; ++mi)
#pragma unroll
            for (int ni = 0; ni < 4; ++ni)
                acc[mi][ni] = __builtin_amdgcn_mfma_f32_16x16x32_bf16(af[mi], bfr[ni], acc[mi][ni], 0, 0, 0);
        __syncthreads();
    }

    unsigned short* ie = inter + (size_t)blockIdx.z * inter_stride;
#pragma unroll
    for (int mi = 0; mi < 4; ++mi)
#pragma unroll
        for (int ni = 0; ni < 4; ++ni)
#pragma unroll
            for (int r = 0; r < 4; ++r) {
                int grow = tm * 128 + wm + mi * 16 + (lane >> 4) * 4 + r;
                int gcol = tn * 128 + wn + ni * 16 + (lane & 15);
                float v = acc[mi][ni][r];
                v = v > 0.f ? v : 0.f;
                ie[(size_t)grow * NI + gcol] = f2bf(v);
            }
}

// ---------------- GEMM2: out[tok[c],h] += w[c] * sum_i inter[c,i] * W2[e][h,i] ----------------
__global__ __launch_bounds__(256) void gemm2_kernel(
    const unsigned short* __restrict__ inter, const float* __restrict__ W2,
    const int* __restrict__ tok_list, const float* __restrict__ w_list,
    float* __restrict__ out, int expert_base, long inter_stride)
{
    const int e    = expert_base + blockIdx.z;
    const int tm   = blockIdx.y;   // 0..31
    const int tn   = blockIdx.x;   // 0..7
    const int tid  = threadIdx.x;
    const int lane = tid & 63;
    const int wave = tid >> 6;
    const int wm   = (wave >> 1) * 64;
    const int wn   = (wave & 1) * 64;

    __shared__ __align__(16) unsigned short Alds[128][40];
    __shared__ __align__(16) unsigned short Blds[128][40];

    const int srow = tid >> 2;
    const int sk0  = (tid & 3) * 8;

    const unsigned short* ie = inter + (size_t)blockIdx.z * inter_stride;
    const float* w2e = W2 + (size_t)e * HID * NI;

    f32x4 acc[4][4];
#pragma unroll
    for (int i = 0; i < 4; ++i)
#pragma unroll
        for (int j = 0; j < 4; ++j) acc[i][j] = (f32x4)0.f;

    for (int k0 = 0; k0 < NI; k0 += 32) {
#pragma unroll
        for (int r2 = 0; r2 < 2; ++r2) {
            int row = srow + r2 * 64;
            // A: bf16 inter, direct 16B copy
            uint4 pa = *reinterpret_cast<const uint4*>(ie + (size_t)(tm * 128 + row) * NI + k0 + sk0);
            *reinterpret_cast<uint4*>(&Alds[row][sk0]) = pa;
            // B: fp32 W2, convert
            const float* srcB = w2e + (size_t)(tn * 128 + row) * NI + k0 + sk0;
            float4 b0 = *reinterpret_cast<const float4*>(srcB);
            float4 b1 = *reinterpret_cast<const float4*>(srcB + 4);
            uint4 pb;
            pb.x = f2bf(b0.x) | ((unsigned)f2bf(b0.y) << 16);
            pb.y = f2bf(b0.z) | ((unsigned)f2bf(b0.w) << 16);
            pb.z = f2bf(b1.x) | ((unsigned)f2bf(b1.y) << 16);
            pb.w = f2bf(b1.z) | ((unsigned)f2bf(b1.w) << 16);
            *reinterpret_cast<uint4*>(&Blds[row][sk0]) = pb;
        }
        __syncthreads();
        s16x8 af[4], bfr[4];
#pragma unroll
        for (int mi = 0; mi < 4; ++mi)
            af[mi] = *reinterpret_cast<const s16x8*>(&Alds[wm + mi * 16 + (lane & 15)][(lane >> 4) * 8]);
#pragma unroll
        for (int ni = 0; ni < 4; ++ni)
            bfr[ni] = *reinterpret_cast<const s16x8*>(&Blds[wn + ni * 16 + (lane & 15)][(lane >> 4) * 8]);
#pragma unroll
        for (int mi = 0; mi < 4; ++mi)
#pragma unroll
            for (int ni = 0; ni < 4; ++ni)
                acc[mi][ni] = __builtin_amdgcn_mfma_f32_16x16x32_bf16(af[mi], bfr[ni], acc[mi][ni], 0, 0, 0);
        __syncthreads();
    }

    const int* tl = tok_list + e * CAP;
    const float* wl = w_list + e * CAP;
#pragma unroll
    for (int mi = 0; mi < 4; ++mi)
#pragma unroll
        for (int r = 0; r < 4; ++r) {
            int slot = tm * 128 + wm + mi * 16 + (lane >> 4) * 4 + r;
            int tok  = tl[slot];
            float w  = wl[slot];
            float* orow = out + (size_t)tok * HID;
#pragma unroll
            for (int ni = 0; ni < 4; ++ni) {
                int gcol = tn * 128 + wn + ni * 16 + (lane & 15);
                atomicAdd(&orow[gcol], acc[mi][ni][r] * w);
            }
        }
}

extern "C" void kernel_launch(void* const* d_in, const int* in_sizes, int n_in,
                              void* d_out, int out_size, void* d_ws, size_t ws_size,
                              hipStream_t stream)
{
    const float* x   = (const float*)d_in[0];
    const float* emb = (const float*)d_in[1];
    const float* W1  = (const float*)d_in[2];
    const float* W2  = (const float*)d_in[3];
    float* out = (float*)d_out;

    size_t off = 0;
    auto alloc = [&](size_t bytes) -> void* {
        void* p = (char*)d_ws + off;
        off += (bytes + 255) & ~(size_t)255;
        return p;
    };
    int*    tok_list = (int*)alloc((size_t)NE * CAP * 4);
    float*  w_list   = (float*)alloc((size_t)NE * CAP * 4);
    int2*   r_e      = (int2*)alloc((size_t)N_TOK * 8);
    float2* r_w      = (float2*)alloc((size_t)N_TOK * 8);
    int*    bc       = (int*)alloc((size_t)(N_TOK / 1024) * NE * 4);
    int*    bb       = (int*)alloc((size_t)(N_TOK / 1024) * NE * 4);
    size_t inter_off = off;
    unsigned short* inter = (unsigned short*)((char*)d_ws + inter_off);
    const size_t per_e = (size_t)CAP * NI;            // elements
    bool batched = ws_size >= inter_off + (size_t)NE * per_e * 2;

    hipMemsetAsync(d_out, 0, (size_t)N_TOK * HID * 4, stream);
    hipMemsetAsync(tok_list, 0, (size_t)NE * CAP * 4, stream);
    hipMemsetAsync(w_list, 0, (size_t)NE * CAP * 4, stream);

    router_kernel<<<N_TOK / 4, 256, 0, stream>>>(x, emb, r_e, r_w);
    count_kernel<<<N_TOK / 1024, 1024, 0, stream>>>(r_e, bc);
    prefix_kernel<<<1, 64, 0, stream>>>(bc, bb);
    assign_kernel<<<N_TOK / 1024, 1024, 0, stream>>>(r_e, r_w, bb, tok_list, w_list);

    if (batched) {
        dim3 g1(NI / 128, CAP / 128, NE);
        dim3 g2(HID / 128, CAP / 128, NE);
        gemm1_kernel<<<g1, 256, 0, stream>>>(x, W1, tok_list, inter, 0, (long)per_e);
        gemm2_kernel<<<g2, 256, 0, stream>>>(inter, W2, tok_list, w_list, out, 0, (long)per_e);
    } else {
        for (int e = 0; e < NE; ++e) {
            dim3 g1(NI / 128, CAP / 128, 1);
            dim3 g2(HID / 128, CAP / 128, 1);
            gemm1_kernel<<<g1, 256, 0, stream>>>(x, W1, tok_list, inter, e, 0);
            gemm2_kernel<<<g2, 256, 0, stream>>>(inter, W2, tok_list, w_list, out, e, 0);
        }
    }
}

// Round 2
// 590.529 us; speedup vs baseline: 1.1850x; 1.1850x over previous
//
#include <hip/hip_runtime.h>
#include <stdint.h>

#define N_TOK 32768
#define HID   1024
#define NE    8
#define NI    2048
#define CAP   4096

typedef short  s16x8 __attribute__((ext_vector_type(8)));
typedef float  f32x4 __attribute__((ext_vector_type(4)));

__device__ __forceinline__ unsigned short f2bf(float f) {
    unsigned int u = __builtin_bit_cast(unsigned int, f);
    u += 0x7fffu + ((u >> 16) & 1u);
    return (unsigned short)(u >> 16);
}

// global -> LDS direct DMA, 16B per lane. LDS dest must be wave-uniform base;
// HW writes lane l at base + l*16.
__device__ __forceinline__ void gload16(const void* g, const void* l) {
    __builtin_amdgcn_global_load_lds(
        (const __attribute__((address_space(1))) unsigned int*)(uintptr_t)g,
        (__attribute__((address_space(3))) unsigned int*)(unsigned int)(uintptr_t)l,
        16, 0, 0);
}

// ---------------- fp32 -> bf16 bulk convert ----------------
__global__ __launch_bounds__(256) void cvt_kernel(
    const float* __restrict__ src, unsigned short* __restrict__ dst, size_t n8)
{
    size_t i = (size_t)blockIdx.x * 256 + threadIdx.x;
    size_t stride = (size_t)gridDim.x * 256;
    for (; i < n8; i += stride) {
        float4 a0 = ((const float4*)src)[2 * i];
        float4 a1 = ((const float4*)src)[2 * i + 1];
        uint4 p;
        p.x = f2bf(a0.x) | ((unsigned)f2bf(a0.y) << 16);
        p.y = f2bf(a0.z) | ((unsigned)f2bf(a0.w) << 16);
        p.z = f2bf(a1.x) | ((unsigned)f2bf(a1.y) << 16);
        p.w = f2bf(a1.z) | ((unsigned)f2bf(a1.w) << 16);
        ((uint4*)dst)[i] = p;
    }
}

// ---------------- Router: fp32 dot, top-2, softmax ----------------
__global__ __launch_bounds__(256) void router_kernel(
    const float* __restrict__ x, const float* __restrict__ emb,
    int2* __restrict__ r_e, float2* __restrict__ r_w)
{
    int token = blockIdx.x * 4 + (threadIdx.x >> 6);
    int lane  = threadIdx.x & 63;
    const float* xr = x + (size_t)token * HID;

    float a[NE];
#pragma unroll
    for (int e = 0; e < NE; ++e) a[e] = 0.f;

    for (int j = 0; j < HID / 64; ++j) {
        int idx = lane + j * 64;
        float xv = xr[idx];
#pragma unroll
        for (int e = 0; e < NE; ++e) a[e] += xv * emb[e * HID + idx];
    }
#pragma unroll
    for (int e = 0; e < NE; ++e) {
        for (int off = 32; off; off >>= 1) a[e] += __shfl_xor(a[e], off);
    }
    if (lane == 0) {
        float v1 = -1e30f, v2 = -1e30f; int i1 = 0, i2 = 0;
#pragma unroll
        for (int e = 0; e < NE; ++e) {
            float v = a[e];
            if (v > v1) { v2 = v1; i2 = i1; v1 = v; i1 = e; }
            else if (v > v2) { v2 = v; i2 = e; }
        }
        float ex = __expf(v2 - v1);
        r_e[token] = make_int2(i1, i2);
        r_w[token] = make_float2(1.f / (1.f + ex), ex / (1.f + ex));
    }
}

// ---------------- Capacity: count / prefix / ordered assign ----------------
__global__ __launch_bounds__(1024) void count_kernel(
    const int2* __restrict__ r_e, int* __restrict__ bc)
{
    __shared__ int cnt[NE];
    if (threadIdx.x < NE) cnt[threadIdx.x] = 0;
    __syncthreads();
    int n = blockIdx.x * 1024 + threadIdx.x;
    int2 e = r_e[n];
    atomicAdd(&cnt[e.x], 1);
    atomicAdd(&cnt[e.y], 1);
    __syncthreads();
    if (threadIdx.x < NE) bc[blockIdx.x * NE + threadIdx.x] = cnt[threadIdx.x];
}

__global__ void prefix_kernel(const int* __restrict__ bc, int* __restrict__ bb)
{
    int e = threadIdx.x;
    if (e >= NE) return;
    int run = 0;
    for (int b = 0; b < N_TOK / 1024; ++b) {
        bb[b * NE + e] = run;
        run += bc[b * NE + e];
    }
}

__global__ __launch_bounds__(1024) void assign_kernel(
    const int2* __restrict__ r_e, const float2* __restrict__ r_w,
    const int* __restrict__ bb,
    int* __restrict__ tok_list, float* __restrict__ w_list)
{
    __shared__ int wavecnt[16][NE];
    __shared__ int waveoff[16][NE];
    int tid = threadIdx.x, lane = tid & 63, wv = tid >> 6;
    int n = blockIdx.x * 1024 + tid;
    int2 e = r_e[n];
    float2 w = r_w[n];
    unsigned long long below = (1ull << lane) - 1ull;
    int rank0 = 0, rank1 = 0;
#pragma unroll
    for (int ex = 0; ex < NE; ++ex) {
        unsigned long long m = __ballot(e.x == ex || e.y == ex);
        if (lane == 0) wavecnt[wv][ex] = __popcll(m);
        int r = __popcll(m & below);
        if (e.x == ex) rank0 = r;
        if (e.y == ex) rank1 = r;
    }
    __syncthreads();
    if (tid < NE) {
        int run = 0;
        for (int w2 = 0; w2 < 16; ++w2) { waveoff[w2][tid] = run; run += wavecnt[w2][tid]; }
    }
    __syncthreads();
    int s0 = bb[blockIdx.x * NE + e.x] + waveoff[wv][e.x] + rank0;
    int s1 = bb[blockIdx.x * NE + e.y] + waveoff[wv][e.y] + rank1;
    if (s0 < CAP) { tok_list[e.x * CAP + s0] = n; w_list[e.x * CAP + s0] = w.x; }
    if (s1 < CAP) { tok_list[e.y * CAP + s1] = n; w_list[e.y * CAP + s1] = w.y; }
}

// Pack 8 fp32 -> uint4 of bf16
__device__ __forceinline__ uint4 pack8(const float* s) {
    float4 a0 = ((const float4*)s)[0];
    float4 a1 = ((const float4*)s)[1];
    uint4 p;
    p.x = f2bf(a0.x) | ((unsigned)f2bf(a0.y) << 16);
    p.y = f2bf(a0.z) | ((unsigned)f2bf(a0.w) << 16);
    p.z = f2bf(a1.x) | ((unsigned)f2bf(a1.y) << 16);
    p.w = f2bf(a1.z) | ((unsigned)f2bf(a1.w) << 16);
    return p;
}

// ---------------- GEMM1: inter = relu(gather(x) @ W1^T), bf16 MFMA ----------------
// Tile 128x128, BK=64, XOR slot-swizzled LDS, global_load_lds when src is bf16.
template<bool ABF, bool BBF>
__global__ __launch_bounds__(256) void gemm1_kernel(
    const unsigned short* __restrict__ xb, const float* __restrict__ xf,
    const unsigned short* __restrict__ w1b, const float* __restrict__ w1f,
    const int* __restrict__ tok_list,
    unsigned short* __restrict__ inter,
    int expert_base, size_t inter_stride)
{
    __shared__ __align__(16) unsigned short smem[128 * 132];
    unsigned short* At = smem;         // [128][64] swizzled
    unsigned short* Bt = smem + 8192;  // [128][64] swizzled

    const int nblk = gridDim.x;
    const int lin  = blockIdx.x;
    const int wg   = (lin & 7) * (nblk >> 3) + (lin >> 3);   // XCD-bijective
    const int tn = wg & 15;            // NI/128 = 16 (fastest: shares A panel + expert L2)
    const int tm = (wg >> 4) & 31;     // CAP/128 = 32
    const int ez = wg >> 9;
    const int e  = expert_base + ez;

    const int tid  = threadIdx.x;
    const int lane = tid & 63;
    const int wave = tid >> 6;
    const int wm = (wave >> 1) * 64;
    const int wn = (wave & 1) * 64;

    const int srow8 = tid >> 3;              // 0..31: row within 32-row stage group
    const int p8    = tid & 7;               // phys 16B slot
    const int gslot = p8 ^ (srow8 & 7);      // pre-swizzled global slot (T2 rule #21)

    const int* tl = tok_list + e * CAP + tm * 128;
    int tok4[4];
#pragma unroll
    for (int c = 0; c < 4; ++c) tok4[c] = tl[c * 32 + srow8];

    const size_t w1off = (size_t)e * NI * HID + (size_t)(tn * 128) * HID;

    f32x4 acc[4][4];
#pragma unroll
    for (int i = 0; i < 4; ++i)
#pragma unroll
        for (int j = 0; j < 4; ++j) acc[i][j] = (f32x4)0.f;

    for (int k0 = 0; k0 < HID; k0 += 64) {
#pragma unroll
        for (int c = 0; c < 4; ++c) {
            const int row = c * 32 + srow8;
            if (ABF) {
                gload16(xb + (size_t)tok4[c] * HID + k0 + gslot * 8,
                        At + (c * 4 + wave) * 512);
            } else {
                *(uint4*)&At[row * 64 + p8 * 8] =
                    pack8(xf + (size_t)tok4[c] * HID + k0 + gslot * 8);
            }
            if (BBF) {
                gload16(w1b + w1off + (size_t)row * HID + k0 + gslot * 8,
                        Bt + (c * 4 + wave) * 512);
            } else {
                *(uint4*)&Bt[row * 64 + p8 * 8] =
                    pack8(w1f + w1off + (size_t)row * HID + k0 + gslot * 8);
            }
        }
        __syncthreads();
#pragma unroll
        for (int ks = 0; ks < 2; ++ks) {
            s16x8 af[4], bf[4];
#pragma unroll
            for (int mi = 0; mi < 4; ++mi) {
                int r  = wm + mi * 16 + (lane & 15);
                int sl = (ks * 4 + (lane >> 4)) ^ (r & 7);
                af[mi] = *(const s16x8*)&At[r * 64 + sl * 8];
            }
#pragma unroll
            for (int ni = 0; ni < 4; ++ni) {
                int r  = wn + ni * 16 + (lane & 15);
                int sl = (ks * 4 + (lane >> 4)) ^ (r & 7);
                bf[ni] = *(const s16x8*)&Bt[r * 64 + sl * 8];
            }
#pragma unroll
            for (int mi = 0; mi < 4; ++mi)
#pragma unroll
                for (int ni = 0; ni < 4; ++ni)
                    acc[mi][ni] = __builtin_amdgcn_mfma_f32_16x16x32_bf16(
                        af[mi], bf[ni], acc[mi][ni], 0, 0, 0);
        }
        __syncthreads();
    }

    // Epilogue: relu -> bf16 repack in LDS (stride 132: conflict-free) -> coalesced 16B stores
#pragma unroll
    for (int mi = 0; mi < 4; ++mi)
#pragma unroll
        for (int ni = 0; ni < 4; ++ni)
#pragma unroll
            for (int r = 0; r < 4; ++r) {
                int row = wm + mi * 16 + (lane >> 4) * 4 + r;
                int col = wn + ni * 16 + (lane & 15);
                float v = acc[mi][ni][r];
                smem[row * 132 + col] = f2bf(v > 0.f ? v : 0.f);
            }
    __syncthreads();
    unsigned short* ie = inter + ez * inter_stride + (size_t)(tm * 128) * NI + tn * 128;
#pragma unroll
    for (int j = 0; j < 8; ++j) {
        int v = tid + j * 256;        // 0..2047
        int row = v >> 4, s = v & 15;
        uint2 lo = *(const uint2*)&smem[row * 132 + s * 8];
        uint2 hi = *(const uint2*)&smem[row * 132 + s * 8 + 4];
        uint4 val; val.x = lo.x; val.y = lo.y; val.z = hi.x; val.w = hi.y;
        *(uint4*)&ie[(size_t)row * NI + s * 8] = val;
    }
}

// ---------------- GEMM2: out[tok] += w * (inter @ W2^T) ----------------
template<bool BBF>
__global__ __launch_bounds__(256) void gemm2_kernel(
    const unsigned short* __restrict__ inter,
    const unsigned short* __restrict__ w2b, const float* __restrict__ w2f,
    const int* __restrict__ tok_list, const float* __restrict__ w_list,
    float* __restrict__ out, int expert_base, size_t inter_stride)
{
    __shared__ __align__(16) unsigned short smem[128 * 64 * 2];
    unsigned short* At = smem;
    unsigned short* Bt = smem + 8192;

    const int nblk = gridDim.x;
    const int lin  = blockIdx.x;
    const int wg   = (lin & 7) * (nblk >> 3) + (lin >> 3);
    const int tn = wg & 7;             // HID/128 = 8
    const int tm = (wg >> 3) & 31;
    const int ez = wg >> 8;
    const int e  = expert_base + ez;

    const int tid  = threadIdx.x;
    const int lane = tid & 63;
    const int wave = tid >> 6;
    const int wm = (wave >> 1) * 64;
    const int wn = (wave & 1) * 64;

    const int srow8 = tid >> 3;
    const int p8    = tid & 7;
    const int gslot = p8 ^ (srow8 & 7);

    const unsigned short* ia = inter + ez * inter_stride + (size_t)(tm * 128) * NI;
    const size_t w2off = (size_t)e * HID * NI + (size_t)(tn * 128) * NI;

    f32x4 acc[4][4];
#pragma unroll
    for (int i = 0; i < 4; ++i)
#pragma unroll
        for (int j = 0; j < 4; ++j) acc[i][j] = (f32x4)0.f;

    for (int k0 = 0; k0 < NI; k0 += 64) {
#pragma unroll
        for (int c = 0; c < 4; ++c) {
            const int row = c * 32 + srow8;
            gload16(ia + (size_t)row * NI + k0 + gslot * 8,
                    At + (c * 4 + wave) * 512);
            if (BBF) {
                gload16(w2b + w2off + (size_t)row * NI + k0 + gslot * 8,
                        Bt + (c * 4 + wave) * 512);
            } else {
                *(uint4*)&Bt[row * 64 + p8 * 8] =
                    pack8(w2f + w2off + (size_t)row * NI + k0 + gslot * 8);
            }
        }
        __syncthreads();
#pragma unroll
        for (int ks = 0; ks < 2; ++ks) {
            s16x8 af[4], bf[4];
#pragma unroll
            for (int mi = 0; mi < 4; ++mi) {
                int r  = wm + mi * 16 + (lane & 15);
                int sl = (ks * 4 + (lane >> 4)) ^ (r & 7);
                af[mi] = *(const s16x8*)&At[r * 64 + sl * 8];
            }
#pragma unroll
            for (int ni = 0; ni < 4; ++ni) {
                int r  = wn + ni * 16 + (lane & 15);
                int sl = (ks * 4 + (lane >> 4)) ^ (r & 7);
                bf[ni] = *(const s16x8*)&Bt[r * 64 + sl * 8];
            }
#pragma unroll
            for (int mi = 0; mi < 4; ++mi)
#pragma unroll
                for (int ni = 0; ni < 4; ++ni)
                    acc[mi][ni] = __builtin_amdgcn_mfma_f32_16x16x32_bf16(
                        af[mi], bf[ni], acc[mi][ni], 0, 0, 0);
        }
        __syncthreads();
    }

    const int* tl = tok_list + e * CAP + tm * 128;
    const float* wl = w_list + e * CAP + tm * 128;
#pragma unroll
    for (int mi = 0; mi < 4; ++mi)
#pragma unroll
        for (int r = 0; r < 4; ++r) {
            int srow = wm + mi * 16 + (lane >> 4) * 4 + r;
            int tok = tl[srow];
            float w = wl[srow];
            float* orow = out + (size_t)tok * HID + tn * 128;
#pragma unroll
            for (int ni = 0; ni < 4; ++ni)
                atomicAdd(&orow[wn + ni * 16 + (lane & 15)], acc[mi][ni][r] * w);
        }
}

extern "C" void kernel_launch(void* const* d_in, const int* in_sizes, int n_in,
                              void* d_out, int out_size, void* d_ws, size_t ws_size,
                              hipStream_t stream)
{
    const float* x   = (const float*)d_in[0];
    const float* emb = (const float*)d_in[1];
    const float* W1  = (const float*)d_in[2];
    const float* W2  = (const float*)d_in[3];
    float* out = (float*)d_out;

    size_t off = 0;
    auto alloc = [&](size_t bytes) -> void* {
        void* p = (char*)d_ws + off;
        off += (bytes + 255) & ~(size_t)255;
        return p;
    };
    int*    tok_list = (int*)alloc((size_t)NE * CAP * 4);
    float*  w_list   = (float*)alloc((size_t)NE * CAP * 4);
    int2*   r_e      = (int2*)alloc((size_t)N_TOK * 8);
    float2* r_w      = (float2*)alloc((size_t)N_TOK * 8);
    int*    bc       = (int*)alloc((size_t)(N_TOK / 1024) * NE * 4);
    int*    bb       = (int*)alloc((size_t)(N_TOK / 1024) * NE * 4);
    const size_t base = off;

    const size_t sz_xb = (size_t)N_TOK * HID * 2;      // 67.1 MB
    const size_t sz_w  = (size_t)NE * NI * HID * 2;    // 33.55 MB each
    const size_t sz_iB = (size_t)NE * CAP * NI * 2;    // 134.2 MB
    const size_t sz_i1 = (size_t)CAP * NI * 2;         // 16.8 MB

    bool cvt_x, cvt_w, batched;
    if      (ws_size >= base + sz_xb + 2 * sz_w + sz_iB) { cvt_x = 1; cvt_w = 1; batched = 1; }
    else if (ws_size >= base + 2 * sz_w + sz_iB)         { cvt_x = 0; cvt_w = 1; batched = 1; }
    else if (ws_size >= base + sz_xb + 2 * sz_w + sz_i1) { cvt_x = 1; cvt_w = 1; batched = 0; }
    else if (ws_size >= base + 2 * sz_w + sz_i1)         { cvt_x = 0; cvt_w = 1; batched = 0; }
    else { cvt_x = 0; cvt_w = 0; batched = (ws_size >= base + sz_iB); }

    unsigned short* xb  = cvt_x ? (unsigned short*)alloc(sz_xb) : nullptr;
    unsigned short* w1b = cvt_w ? (unsigned short*)alloc(sz_w)  : nullptr;
    unsigned short* w2b = cvt_w ? (unsigned short*)alloc(sz_w)  : nullptr;
    unsigned short* inter = (unsigned short*)alloc(batched ? sz_iB : sz_i1);
    const size_t istride = batched ? (size_t)CAP * NI : 0;

    hipMemsetAsync(d_out, 0, (size_t)N_TOK * HID * 4, stream);
    hipMemsetAsync(tok_list, 0, (size_t)NE * CAP * 4, stream);
    hipMemsetAsync(w_list, 0, (size_t)NE * CAP * 4, stream);

    if (cvt_x) cvt_kernel<<<2048, 256, 0, stream>>>(x, xb, (size_t)N_TOK * HID / 8);
    if (cvt_w) {
        cvt_kernel<<<2048, 256, 0, stream>>>(W1, w1b, (size_t)NE * NI * HID / 8);
        cvt_kernel<<<2048, 256, 0, stream>>>(W2, w2b, (size_t)NE * HID * NI / 8);
    }

    router_kernel<<<N_TOK / 4, 256, 0, stream>>>(x, emb, r_e, r_w);
    count_kernel<<<N_TOK / 1024, 1024, 0, stream>>>(r_e, bc);
    prefix_kernel<<<1, 64, 0, stream>>>(bc, bb);
    assign_kernel<<<N_TOK / 1024, 1024, 0, stream>>>(r_e, r_w, bb, tok_list, w_list);

    const int nz = batched ? NE : 1;
    const int n1 = 16 * 32 * nz;
    const int n2 = 8 * 32 * nz;
    for (int eb = 0; eb < NE; eb += (batched ? NE : 1)) {
        if (cvt_x && cvt_w)
            gemm1_kernel<true, true><<<n1, 256, 0, stream>>>(
                xb, nullptr, w1b, nullptr, tok_list, inter, eb, istride);
        else if (cvt_w)
            gemm1_kernel<false, true><<<n1, 256, 0, stream>>>(
                nullptr, x, w1b, nullptr, tok_list, inter, eb, istride);
        else
            gemm1_kernel<false, false><<<n1, 256, 0, stream>>>(
                nullptr, x, nullptr, W1, tok_list, inter, eb, istride);

        if (cvt_w)
            gemm2_kernel<true><<<n2, 256, 0, stream>>>(
                inter, w2b, nullptr, tok_list, w_list, out, eb, istride);
        else
            gemm2_kernel<false><<<n2, 256, 0, stream>>>(
                inter, nullptr, W2, tok_list, w_list, out, eb, istride);
    }
}

// Round 3
// 471.436 us; speedup vs baseline: 1.4844x; 1.2526x over previous
//
#include <hip/hip_runtime.h>
#include <stdint.h>

#define N_TOK 32768
#define HID   1024
#define NE    8
#define NI    2048
#define CAP   4096

typedef short s16x8 __attribute__((ext_vector_type(8)));
typedef float f32x4 __attribute__((ext_vector_type(4)));

__device__ __forceinline__ unsigned short f2bf(float f) {
    unsigned int u = __builtin_bit_cast(unsigned int, f);
    u += 0x7fffu + ((u >> 16) & 1u);
    return (unsigned short)(u >> 16);
}

__device__ __forceinline__ void gload16(const void* g, void* l) {
    __builtin_amdgcn_global_load_lds(
        (const __attribute__((address_space(1))) unsigned int*)(uintptr_t)g,
        (__attribute__((address_space(3))) unsigned int*)(unsigned int)(uintptr_t)l,
        16, 0, 0);
}

#define WAIT_LGKM0 asm volatile("s_waitcnt lgkmcnt(0)" ::: "memory")
#define WAIT_VM6   asm volatile("s_waitcnt vmcnt(6)" ::: "memory")
#define WAIT_VM0   asm volatile("s_waitcnt vmcnt(0)" ::: "memory")
#define SFENCE     __builtin_amdgcn_sched_barrier(0)
#define BARR       __builtin_amdgcn_s_barrier()

// stage one 128x64 half-tile (2 x 1024B wave loads), pre-swizzled global slot
#define STAGE(Ms, rM, tile, h) do { \
    unsigned short* _d = Ms + (((tile) & 1) * 16384) + (h) * 8192 + wave * 1024; \
    gload16(rM[h][0] + (tile) * 64 + gsl8, _d); \
    gload16(rM[h][1] + (tile) * 64 + gsl8, _d + 512); } while (0)

#define MFMA16(AF, BF, NP) do { \
    __builtin_amdgcn_s_setprio(1); \
    _Pragma("unroll") \
    for (int mi = 0; mi < 8; ++mi) { \
        acc[mi][(NP)*2]   = __builtin_amdgcn_mfma_f32_16x16x32_bf16(AF[mi], BF[(NP)*2],   acc[mi][(NP)*2],   0, 0, 0); \
        acc[mi][(NP)*2+1] = __builtin_amdgcn_mfma_f32_16x16x32_bf16(AF[mi], BF[(NP)*2+1], acc[mi][(NP)*2+1], 0, 0, 0); \
    } \
    __builtin_amdgcn_s_setprio(0); \
} while (0)

// ---------------- fp32 -> bf16 bulk convert ----------------
__global__ __launch_bounds__(256) void cvt_kernel(
    const float* __restrict__ src, unsigned short* __restrict__ dst, size_t n8)
{
    size_t i = (size_t)blockIdx.x * 256 + threadIdx.x;
    size_t stride = (size_t)gridDim.x * 256;
    for (; i < n8; i += stride) {
        float4 a0 = ((const float4*)src)[2 * i];
        float4 a1 = ((const float4*)src)[2 * i + 1];
        uint4 p;
        p.x = f2bf(a0.x) | ((unsigned)f2bf(a0.y) << 16);
        p.y = f2bf(a0.z) | ((unsigned)f2bf(a0.w) << 16);
        p.z = f2bf(a1.x) | ((unsigned)f2bf(a1.y) << 16);
        p.w = f2bf(a1.z) | ((unsigned)f2bf(a1.w) << 16);
        ((uint4*)dst)[i] = p;
    }
}

// ---------------- Router: fp32 dot, top-2, softmax; fused x->bf16 ----------------
__global__ __launch_bounds__(256) void router_kernel(
    const float* __restrict__ x, const float* __restrict__ emb,
    int2* __restrict__ r_e, float2* __restrict__ r_w,
    unsigned short* __restrict__ xb)
{
    int token = blockIdx.x * 4 + (threadIdx.x >> 6);
    int lane  = threadIdx.x & 63;
    const float4* xr = (const float4*)(x + (size_t)token * HID);
    const float4* er = (const float4*)emb;

    float a[NE];
#pragma unroll
    for (int e = 0; e < NE; ++e) a[e] = 0.f;
    uint2 pk[4];
#pragma unroll
    for (int j = 0; j < 4; ++j) {
        float4 v = xr[j * 64 + lane];
        pk[j].x = f2bf(v.x) | ((unsigned)f2bf(v.y) << 16);
        pk[j].y = f2bf(v.z) | ((unsigned)f2bf(v.w) << 16);
#pragma unroll
        for (int e = 0; e < NE; ++e) {
            float4 w = er[e * 256 + j * 64 + lane];
            a[e] += v.x * w.x + v.y * w.y + v.z * w.z + v.w * w.w;
        }
    }
    uint2* xbr = (uint2*)(xb + (size_t)token * HID);
#pragma unroll
    for (int j = 0; j < 4; ++j) xbr[j * 64 + lane] = pk[j];

#pragma unroll
    for (int e = 0; e < NE; ++e) {
        for (int off = 32; off; off >>= 1) a[e] += __shfl_xor(a[e], off);
    }
    if (lane == 0) {
        float v1 = -1e30f, v2 = -1e30f; int i1 = 0, i2 = 0;
#pragma unroll
        for (int e = 0; e < NE; ++e) {
            float v = a[e];
            if (v > v1) { v2 = v1; i2 = i1; v1 = v; i1 = e; }
            else if (v > v2) { v2 = v; i2 = e; }
        }
        float ex = __expf(v2 - v1);
        r_e[token] = make_int2(i1, i2);
        r_w[token] = make_float2(1.f / (1.f + ex), ex / (1.f + ex));
    }
}

// ---------------- Capacity: count / prefix / ordered assign ----------------
__global__ __launch_bounds__(1024) void count_kernel(
    const int2* __restrict__ r_e, int* __restrict__ bc)
{
    __shared__ int cnt[NE];
    if (threadIdx.x < NE) cnt[threadIdx.x] = 0;
    __syncthreads();
    int n = blockIdx.x * 1024 + threadIdx.x;
    int2 e = r_e[n];
    atomicAdd(&cnt[e.x], 1);
    atomicAdd(&cnt[e.y], 1);
    __syncthreads();
    if (threadIdx.x < NE) bc[blockIdx.x * NE + threadIdx.x] = cnt[threadIdx.x];
}

__global__ void prefix_kernel(const int* __restrict__ bc, int* __restrict__ bb)
{
    int e = threadIdx.x;
    if (e >= NE) return;
    int run = 0;
    for (int b = 0; b < N_TOK / 1024; ++b) {
        bb[b * NE + e] = run;
        run += bc[b * NE + e];
    }
}

__global__ __launch_bounds__(1024) void assign_kernel(
    const int2* __restrict__ r_e, const float2* __restrict__ r_w,
    const int* __restrict__ bb,
    int* __restrict__ tok_list, float* __restrict__ w_list)
{
    __shared__ int wavecnt[16][NE];
    __shared__ int waveoff[16][NE];
    int tid = threadIdx.x, lane = tid & 63, wv = tid >> 6;
    int n = blockIdx.x * 1024 + tid;
    int2 e = r_e[n];
    float2 w = r_w[n];
    unsigned long long below = (1ull << lane) - 1ull;
    int rank0 = 0, rank1 = 0;
#pragma unroll
    for (int ex = 0; ex < NE; ++ex) {
        unsigned long long m = __ballot(e.x == ex || e.y == ex);
        if (lane == 0) wavecnt[wv][ex] = __popcll(m);
        int r = __popcll(m & below);
        if (e.x == ex) rank0 = r;
        if (e.y == ex) rank1 = r;
    }
    __syncthreads();
    if (tid < NE) {
        int run = 0;
        for (int w2 = 0; w2 < 16; ++w2) { waveoff[w2][tid] = run; run += wavecnt[w2][tid]; }
    }
    __syncthreads();
    int s0 = bb[blockIdx.x * NE + e.x] + waveoff[wv][e.x] + rank0;
    int s1 = bb[blockIdx.x * NE + e.y] + waveoff[wv][e.y] + rank1;
    if (s0 < CAP) { tok_list[e.x * CAP + s0] = n; w_list[e.x * CAP + s0] = w.x; }
    if (s1 < CAP) { tok_list[e.y * CAP + s1] = n; w_list[e.y * CAP + s1] = w.y; }
}

// ---------------- GEMM1: 256x256 tile, 4-phase counted-vmcnt pipeline ----------------
__global__ __launch_bounds__(512, 2) void gemm1_k(
    const unsigned short* __restrict__ xb,
    const unsigned short* __restrict__ w1b,
    const int* __restrict__ tok_list,
    unsigned short* __restrict__ inter,
    int eb)
{
    constexpr int K = HID, T = K / 64, NTN = NI / 256;
    __shared__ __align__(16) unsigned short smem[65536];
    unsigned short* As = smem;
    unsigned short* Bs = smem + 32768;

    const int nblk = gridDim.x;
    const int lin  = blockIdx.x;
    const int wg   = (lin & 7) * (nblk >> 3) + (lin >> 3);
    const int tn = wg % NTN;
    const int tm = (wg / NTN) & 15;
    const int ez = wg / (NTN * 16);
    const int e  = eb + ez;

    const int tid = threadIdx.x, lane = tid & 63, wave = tid >> 6;
    const int wr = wave >> 2, wc = wave & 3;
    const int gsl8 = ((lane & 7) ^ (lane >> 3)) * 8;
    const int aoff = (wr * 128 + (lane & 15)) * 64;
    const int boff = (wc * 64 + (lane & 15)) * 64;
    const int ph0 = ((lane >> 4) ^ (lane & 7)) * 8;
    const int ph1 = ((4 + (lane >> 4)) ^ (lane & 7)) * 8;
    const int rbase = wave * 16 + (lane >> 3);

    const int* tl = tok_list + e * CAP + tm * 256;
    const unsigned short* rA[2][2];
    const unsigned short* rB[2][2];
#pragma unroll
    for (int h = 0; h < 2; ++h)
#pragma unroll
        for (int j = 0; j < 2; ++j) {
            rA[h][j] = xb + (size_t)tl[h * 128 + rbase + j * 8] * K;
            rB[h][j] = w1b + ((size_t)e * NI + tn * 256 + h * 128 + rbase + j * 8) * K;
        }

    f32x4 acc[8][4];
#pragma unroll
    for (int i = 0; i < 8; ++i)
#pragma unroll
        for (int j = 0; j < 4; ++j) acc[i][j] = (f32x4)0.f;

    s16x8 afr[8], bfr0[4], bfr1[4];

    // prologue: tile0 all halves + tile1 B0,B1,A0
    STAGE(As, rA, 0, 0); STAGE(As, rA, 0, 1);
    STAGE(Bs, rB, 0, 0); STAGE(Bs, rB, 0, 1);
    STAGE(Bs, rB, 1, 0); STAGE(Bs, rB, 1, 1);
    STAGE(As, rA, 1, 0);
    WAIT_VM6; SFENCE; BARR; SFENCE;

#pragma unroll 2
    for (int t = 0; t < T; ++t) {
        const int buf = (t & 1) * 16384;
        // -------- phase 0: read A-k0 + all B; stage A1(t+1) --------
        if (t + 1 < T) STAGE(As, rA, t + 1, 1);
#pragma unroll
        for (int mi = 0; mi < 8; ++mi)
            afr[mi] = *(const s16x8*)(As + buf + aoff + mi * 1024 + ph0);
#pragma unroll
        for (int ni = 0; ni < 4; ++ni) {
            bfr0[ni] = *(const s16x8*)(Bs + buf + boff + ni * 1024 + ph0);
            bfr1[ni] = *(const s16x8*)(Bs + buf + boff + ni * 1024 + ph1);
        }
        WAIT_LGKM0; SFENCE; BARR; SFENCE;
        MFMA16(afr, bfr0, 0);
        // -------- phase 1: stage B0(t+2) --------
        if (t + 2 < T) STAGE(Bs, rB, t + 2, 0);
        BARR; SFENCE;
        MFMA16(afr, bfr0, 1);
        // -------- phase 2: read A-k1; stage B1(t+2) --------
        if (t + 2 < T) STAGE(Bs, rB, t + 2, 1);
#pragma unroll
        for (int mi = 0; mi < 8; ++mi)
            afr[mi] = *(const s16x8*)(As + buf + aoff + mi * 1024 + ph1);
        WAIT_LGKM0; SFENCE; BARR; SFENCE;
        MFMA16(afr, bfr1, 0);
        // -------- phase 3: stage A0(t+2); counted vmcnt --------
        if (t + 2 < T) STAGE(As, rA, t + 2, 0);
        if (t < T - 2) { WAIT_VM6; } else { WAIT_VM0; }
        SFENCE; BARR; SFENCE;
        MFMA16(afr, bfr1, 1);
    }

    // epilogue: relu + swizzled LDS repack -> coalesced 16B stores
#pragma unroll
    for (int mi = 0; mi < 8; ++mi)
#pragma unroll
        for (int ni = 0; ni < 4; ++ni)
#pragma unroll
            for (int r = 0; r < 4; ++r) {
                int row = wr * 128 + mi * 16 + (lane >> 4) * 4 + r;
                int c   = wc * 64 + ni * 16 + (lane & 15);
                float v = acc[mi][ni][r];
                v = v > 0.f ? v : 0.f;
                smem[row * 256 + (((c >> 3) ^ (row & 7)) << 3) + (c & 7)] = f2bf(v);
            }
    __syncthreads();
    unsigned short* Cp = inter + ((size_t)ez * CAP + tm * 256) * NI + tn * 256;
#pragma unroll
    for (int it = 0; it < 16; ++it) {
        int v = tid + it * 512;
        int row = v >> 5, s = v & 31;
        uint4 val = *(const uint4*)&smem[row * 256 + ((s ^ (row & 7)) << 3)];
        *(uint4*)&Cp[(size_t)row * NI + s * 8] = val;
    }
}

// ---------------- GEMM2: same pipeline; atomic fp32 combine epilogue ----------------
__global__ __launch_bounds__(512, 2) void gemm2_k(
    const unsigned short* __restrict__ inter,
    const unsigned short* __restrict__ w2b,
    const int* __restrict__ tok_list,
    const float* __restrict__ w_list,
    float* __restrict__ out,
    int eb)
{
    constexpr int K = NI, T = K / 64, NTN = HID / 256;
    __shared__ __align__(16) unsigned short smem[65536];
    unsigned short* As = smem;
    unsigned short* Bs = smem + 32768;

    const int nblk = gridDim.x;
    const int lin  = blockIdx.x;
    const int wg   = (lin & 7) * (nblk >> 3) + (lin >> 3);
    const int tn = wg % NTN;
    const int tm = (wg / NTN) & 15;
    const int ez = wg / (NTN * 16);
    const int e  = eb + ez;

    const int tid = threadIdx.x, lane = tid & 63, wave = tid >> 6;
    const int wr = wave >> 2, wc = wave & 3;
    const int gsl8 = ((lane & 7) ^ (lane >> 3)) * 8;
    const int aoff = (wr * 128 + (lane & 15)) * 64;
    const int boff = (wc * 64 + (lane & 15)) * 64;
    const int ph0 = ((lane >> 4) ^ (lane & 7)) * 8;
    const int ph1 = ((4 + (lane >> 4)) ^ (lane & 7)) * 8;
    const int rbase = wave * 16 + (lane >> 3);

    const unsigned short* rA[2][2];
    const unsigned short* rB[2][2];
#pragma unroll
    for (int h = 0; h < 2; ++h)
#pragma unroll
        for (int j = 0; j < 2; ++j) {
            rA[h][j] = inter + ((size_t)ez * CAP + tm * 256 + h * 128 + rbase + j * 8) * (size_t)K;
            rB[h][j] = w2b + ((size_t)e * HID + tn * 256 + h * 128 + rbase + j * 8) * (size_t)K;
        }

    f32x4 acc[8][4];
#pragma unroll
    for (int i = 0; i < 8; ++i)
#pragma unroll
        for (int j = 0; j < 4; ++j) acc[i][j] = (f32x4)0.f;

    s16x8 afr[8], bfr0[4], bfr1[4];

    STAGE(As, rA, 0, 0); STAGE(As, rA, 0, 1);
    STAGE(Bs, rB, 0, 0); STAGE(Bs, rB, 0, 1);
    STAGE(Bs, rB, 1, 0); STAGE(Bs, rB, 1, 1);
    STAGE(As, rA, 1, 0);
    WAIT_VM6; SFENCE; BARR; SFENCE;

#pragma unroll 2
    for (int t = 0; t < T; ++t) {
        const int buf = (t & 1) * 16384;
        if (t + 1 < T) STAGE(As, rA, t + 1, 1);
#pragma unroll
        for (int mi = 0; mi < 8; ++mi)
            afr[mi] = *(const s16x8*)(As + buf + aoff + mi * 1024 + ph0);
#pragma unroll
        for (int ni = 0; ni < 4; ++ni) {
            bfr0[ni] = *(const s16x8*)(Bs + buf + boff + ni * 1024 + ph0);
            bfr1[ni] = *(const s16x8*)(Bs + buf + boff + ni * 1024 + ph1);
        }
        WAIT_LGKM0; SFENCE; BARR; SFENCE;
        MFMA16(afr, bfr0, 0);
        if (t + 2 < T) STAGE(Bs, rB, t + 2, 0);
        BARR; SFENCE;
        MFMA16(afr, bfr0, 1);
        if (t + 2 < T) STAGE(Bs, rB, t + 2, 1);
#pragma unroll
        for (int mi = 0; mi < 8; ++mi)
            afr[mi] = *(const s16x8*)(As + buf + aoff + mi * 1024 + ph1);
        WAIT_LGKM0; SFENCE; BARR; SFENCE;
        MFMA16(afr, bfr1, 0);
        if (t + 2 < T) STAGE(As, rA, t + 2, 0);
        if (t < T - 2) { WAIT_VM6; } else { WAIT_VM0; }
        SFENCE; BARR; SFENCE;
        MFMA16(afr, bfr1, 1);
    }

    const int* tl   = tok_list + e * CAP + tm * 256;
    const float* wl = w_list  + e * CAP + tm * 256;
#pragma unroll
    for (int mi = 0; mi < 8; ++mi)
#pragma unroll
        for (int r = 0; r < 4; ++r) {
            int rrow = wr * 128 + mi * 16 + (lane >> 4) * 4 + r;
            int tok  = tl[rrow];
            float w  = wl[rrow];
            float* orow = out + (size_t)tok * HID + tn * 256 + wc * 64;
#pragma unroll
            for (int ni = 0; ni < 4; ++ni)
                atomicAdd(&orow[ni * 16 + (lane & 15)], acc[mi][ni][r] * w);
        }
}

extern "C" void kernel_launch(void* const* d_in, const int* in_sizes, int n_in,
                              void* d_out, int out_size, void* d_ws, size_t ws_size,
                              hipStream_t stream)
{
    const float* x   = (const float*)d_in[0];
    const float* emb = (const float*)d_in[1];
    const float* W1  = (const float*)d_in[2];
    const float* W2  = (const float*)d_in[3];
    float* out = (float*)d_out;

    size_t off = 0;
    auto alloc = [&](size_t bytes) -> void* {
        void* p = (char*)d_ws + off;
        off += (bytes + 255) & ~(size_t)255;
        return p;
    };
    const size_t sz_w  = (size_t)NE * NI * HID * 2;   // 33,554,432
    const size_t sz_xb = (size_t)N_TOK * HID * 2;     // 67,108,864

    int*   tok_list = (int*)alloc((size_t)NE * CAP * 4);
    float* w_list   = (float*)alloc((size_t)NE * CAP * 4);
    unsigned short* w1b = (unsigned short*)alloc(sz_w);
    unsigned short* w2b = (unsigned short*)alloc(sz_w);
    unsigned short* xb  = (unsigned short*)alloc(sz_xb);

    unsigned short* inter = (unsigned short*)((char*)d_ws + off);
    size_t avail = ws_size > off ? ws_size - off : 0;
    const size_t per_e = (size_t)CAP * NI * 2;        // 16,777,216
    int G = (avail >= 8 * per_e) ? 8 : (avail >= 4 * per_e) ? 4
          : (avail >= 2 * per_e) ? 2 : 1;

    // transient router/capacity scratch lives at the head of the inter region
    int2*   r_e = (int2*)inter;
    float2* r_w = (float2*)((char*)inter + (size_t)N_TOK * 8);
    int*    bc  = (int*)((char*)inter + (size_t)N_TOK * 16);
    int*    bb  = bc + (N_TOK / 1024) * NE;

    hipMemsetAsync(d_out, 0, (size_t)N_TOK * HID * 4, stream);
    hipMemsetAsync(tok_list, 0, (size_t)NE * CAP * 4, stream);
    hipMemsetAsync(w_list, 0, (size_t)NE * CAP * 4, stream);

    cvt_kernel<<<2048, 256, 0, stream>>>(W1, w1b, (size_t)NE * NI * HID / 8);
    cvt_kernel<<<2048, 256, 0, stream>>>(W2, w2b, (size_t)NE * HID * NI / 8);
    router_kernel<<<N_TOK / 4, 256, 0, stream>>>(x, emb, r_e, r_w, xb);
    count_kernel<<<N_TOK / 1024, 1024, 0, stream>>>(r_e, bc);
    prefix_kernel<<<1, 64, 0, stream>>>(bc, bb);
    assign_kernel<<<N_TOK / 1024, 1024, 0, stream>>>(r_e, r_w, bb, tok_list, w_list);

    for (int eb = 0; eb < NE; eb += G) {
        gemm1_k<<<dim3((NI / 256) * 16 * G), 512, 0, stream>>>(xb, w1b, tok_list, inter, eb);
        gemm2_k<<<dim3((HID / 256) * 16 * G), 512, 0, stream>>>(inter, w2b, tok_list, w_list, out, eb);
    }
}